// Round 17
// baseline (398.544 us; speedup 1.0000x reference)
//
#include <hip/hip_runtime.h>
#include <cstdint>
#include <cstddef>

// Problem constants
#define B_ 2
#define S_ 2048
#define D_ 2048
#define H_ 16
#define HD_ 128
#define NTOK 4096       // B_*S_
#define NQKV 6144       // 3*D_

typedef unsigned short u16;
typedef __attribute__((ext_vector_type(8))) __bf16 bf16x8;
typedef __attribute__((ext_vector_type(4))) float f32x4;

// fp32 -> bf16 (RNE)
__device__ __forceinline__ u16 f2bf(float f) {
  uint32_t u = __builtin_bit_cast(uint32_t, f);
  u = (u + 0x7FFFu + ((u >> 16) & 1u)) >> 16;
  return (u16)u;
}

__device__ __forceinline__ void gload_lds16(const void* g, void* l) {
  __builtin_amdgcn_global_load_lds(
      (const __attribute__((address_space(1))) void*)g,
      (__attribute__((address_space(3))) void*)l, 16, 0, 0);
}

// ---------------- merged conversion kernel (3 tensors, one launch) ----------------
__global__ void cvt_all(const float* __restrict__ hs, const float* __restrict__ wqkv,
                        const float* __restrict__ wo,
                        u16* __restrict__ hsb, u16* __restrict__ wqkvb,
                        u16* __restrict__ wob) {
  const int n1 = (B_ * S_ * D_) / 8;
  const int n2 = n1 + (NQKV * D_) / 8;
  const int n3 = n2 + (D_ * D_) / 8;
  int idx = blockIdx.x * blockDim.x + threadIdx.x;
  int stride = gridDim.x * blockDim.x;
  for (int i = idx; i < n3; i += stride) {
    const float* src; u16* dst; int j;
    if (i < n1)      { src = hs;   dst = hsb;   j = i; }
    else if (i < n2) { src = wqkv; dst = wqkvb; j = i - n1; }
    else             { src = wo;   dst = wob;   j = i - n2; }
    const float4* s = (const float4*)(src + (size_t)j * 8);
    float4 a = s[0], b = s[1];
    union { u16 u[8]; uint4 v; } o;
    o.u[0] = f2bf(a.x); o.u[1] = f2bf(a.y); o.u[2] = f2bf(a.z); o.u[3] = f2bf(a.w);
    o.u[4] = f2bf(b.x); o.u[5] = f2bf(b.y); o.u[6] = f2bf(b.z); o.u[7] = f2bf(b.w);
    *(uint4*)(dst + (size_t)j * 8) = o.v;
  }
}

// ---------------- shared phase macros ----------------
#define PH_MID() do { asm volatile("s_barrier" ::: "memory"); \
  __builtin_amdgcn_s_setprio(1); } while (0)
#define PH_END() do { __builtin_amdgcn_s_setprio(0); \
  asm volatile("s_barrier" ::: "memory"); } while (0)
#define PH_END_VM(n) do { __builtin_amdgcn_s_setprio(0); \
  asm volatile("s_waitcnt vmcnt(" #n ")" ::: "memory"); \
  asm volatile("s_barrier" ::: "memory"); } while (0)

// ======== QKV GEMM v7: B served from L2 (reg ping-pong), A-only LDS ========
// Diagnosis (round 16): LDS read-port bound — per CU-tile 224 ds_read_b128
// (2688 cyc at 12cyc/ea) vs 1862 cyc MFMA => MfmaUtil capped ~37% (measured).
// Fix: B-frags (6/14 reads, only 2-way reuse) load directly from global into
// ping-pong regs bgA/bgB, prefetched ONE TILE ahead (flight ~= full tile >>
// L2 latency; each instr = 16 fully-used 64B lines). LDS now A-only:
// 8 reads/wave/tile -> port 1536 cyc < MFMA 1862 -> MFMA-bound.
// LDS = 2 x 16 KiB (A dbuf). vmcnt ledger: per tile issue [A(t+1)x2 stages,
// then B(t+1)x6 loads]; tile-end vmcnt(6) retires exactly A(t+1), keeps B
// in flight (consumed next tile via compiler auto-wait). Prologue: A(0)+B(0),
// vmcnt(6) retires A(0). Tail: t30 stages A(31)+prefs B(31); t31 bare.
// WAR: STA into buf^1 at tile t — buf^1's A-reads (tile t-1) were consumed
// by t-1's MFMA before t-1's end barrier. Single ar[2][2] reused per phase
// (VGPR budget: acc48+ar16+bg48+addr ~= 124 <= 128 cap from launch_bounds).

#define STA(sl,buf,ko) gload_lds16(aSrc + (size_t)(sl)*64*D_ + (ko), aDst + (buf)*8192 + (sl)*4096)

#define LDA(buf,q) do { _Pragma("unroll") for (int mm = 0; mm < 2; ++mm) \
  _Pragma("unroll") for (int kk = 0; kk < 2; ++kk) \
    ar[mm][kk] = *(const bf16x8*)(sA + (buf)*8192 + (wm*64 + ((q)*2+mm)*16 + fr)*64 + ((((kk<<2)|fq)^swz)<<3)); } while (0)
#define PREFB(bg, ko) do { _Pragma("unroll") for (int nf = 0; nf < 3; ++nf) \
  _Pragma("unroll") for (int kk = 0; kk < 2; ++kk) \
    bg[nf][kk] = *(const bf16x8*)(bBase + (size_t)nf * 16 * D_ + (ko) + kk * 32); } while (0)
#define MFMA12G(bg, base) do { _Pragma("unroll") for (int kk = 0; kk < 2; ++kk) \
  _Pragma("unroll") for (int mm = 0; mm < 2; ++mm) \
  _Pragma("unroll") for (int nf = 0; nf < 3; ++nf) \
    acc[(base)+mm][nf] = __builtin_amdgcn_mfma_f32_16x16x32_bf16(ar[mm][kk], bg[nf][kk], acc[(base)+mm][nf], 0, 0, 0); } while (0)

__global__ __launch_bounds__(512, 4) void qkv_gemm(
    const u16* __restrict__ hsb, const u16* __restrict__ wb,
    const float* __restrict__ bias,
    u16* __restrict__ qb, u16* __restrict__ kb, u16* __restrict__ vT)
{
  __shared__ alignas(1024) u16 sA[2 * 8192];    // 32 KiB (A only)
  const int tid = threadIdx.x;
  const int lane = tid & 63, wid = tid >> 6;
  const int wm = wid >> 2, wn = wid & 3;
  const int fr = lane & 15, fq = lane >> 4;
  const int swz = fr & 7;
  const int m0 = blockIdx.x * 128, n0 = blockIdx.y * 192;

  const int r8 = tid >> 3, g8 = (tid & 7) ^ (r8 & 7);
  const u16* aSrc = hsb + (size_t)(m0 + r8) * D_ + g8 * 8;
  u16* aDst = sA + wid * 512;
  // per-lane B base: row n0+wn*48+fr, col fq*8 (nf/kk/k0 added as offsets)
  const u16* bBase = wb + (size_t)(n0 + wn * 48 + fr) * D_ + fq * 8;

  f32x4 acc[4][3];
  f32x4 z = {0.f, 0.f, 0.f, 0.f};
#pragma unroll
  for (int m = 0; m < 4; ++m)
#pragma unroll
    for (int n = 0; n < 3; ++n) acc[m][n] = z;

  bf16x8 ar[2][2];
  bf16x8 bgA[3][2], bgB[3][2];

  // prologue: A(0)->buf0 (2 stages), B(0)->bgA (6 loads); vmcnt(6) retires A(0)
  STA(0,0,0); STA(1,0,0);
  PREFB(bgA, 0);
  asm volatile("s_waitcnt vmcnt(6)" ::: "memory");
  asm volatile("s_barrier" ::: "memory");

#pragma unroll 1
  for (int j = 0; j < 15; ++j) {                 // tiles 0..29 (15 pairs)
    const int kN1 = (2*j + 1) * 64;              // next tile for even member
    const int kN2 = (2*j + 2) * 64;              // next tile for odd member
    // tile 2j (buf0, bgA): stage A(2j+1)->buf1, prefetch B(2j+1)->bgB
    LDA(0,0); STA(0,1,kN1); STA(1,1,kN1); PREFB(bgB, kN1);
      PH_MID(); MFMA12G(bgA, 0); PH_END();
    LDA(0,1);
      PH_MID(); MFMA12G(bgA, 2); PH_END_VM(6);
    // tile 2j+1 (buf1, bgB): stage A(2j+2)->buf0, prefetch B(2j+2)->bgA
    LDA(1,0); STA(0,0,kN2); STA(1,0,kN2); PREFB(bgA, kN2);
      PH_MID(); MFMA12G(bgB, 0); PH_END();
    LDA(1,1);
      PH_MID(); MFMA12G(bgB, 2); PH_END_VM(6);
  }
  { // tail: tile 30 (buf0,bgA; stage A31+pref B31), tile 31 (buf1,bgB; bare)
    const int k31 = 31 * 64;
    LDA(0,0); STA(0,1,k31); STA(1,1,k31); PREFB(bgB, k31);
      PH_MID(); MFMA12G(bgA, 0); PH_END();
    LDA(0,1);
      PH_MID(); MFMA12G(bgA, 2); PH_END_VM(6);
    LDA(1,0);
      PH_MID(); MFMA12G(bgB, 0); PH_END();
    LDA(1,1);
      PH_MID(); MFMA12G(bgB, 2); PH_END();
  }

  // epilogue: scatter q (pre-scaled), k, vT
  const float qscale = 0.08838834764831845f; // 1/sqrt(128)
#pragma unroll
  for (int mf = 0; mf < 4; ++mf)
#pragma unroll
    for (int nf = 0; nf < 3; ++nf) {
      int col = n0 + wn * 48 + nf * 16 + fr;     // 0..6143
      float bv = bias[col];
      int t = col >> 11;                          // 0=q 1=k 2=v
      int d2 = col & 2047;
      int h = d2 >> 7, hd = d2 & 127;
#pragma unroll
      for (int r = 0; r < 4; ++r) {
        int row = m0 + wm * 64 + mf * 16 + fq * 4 + r;    // 0..4095
        int bb = row >> 11, s = row & 2047;
        int bh = bb * H_ + h;
        float val = acc[mf][nf][r] + bv;
        if (t == 0)      qb[((size_t)bh * S_ + s) * HD_ + hd] = f2bf(val * qscale);
        else if (t == 1) kb[((size_t)bh * S_ + s) * HD_ + hd] = f2bf(val);
        else             vT[((size_t)bh * HD_ + hd) * S_ + s] = f2bf(val);
      }
    }
}

// ======== OUT GEMM: BM=128 x BN=128, BK=64, 64 KiB, 2 blocks/CU (round-14) ========
#define OSTA(sl,buf,ko) gload_lds16(aSrcO + (size_t)(sl)*64*D_ + (ko), aDstO + (buf)*8192 + (sl)*4096)
#define OSTB(sl,buf,ko) gload_lds16(bSrcO + (size_t)(sl)*64*D_ + (ko), bDstO + (buf)*8192 + (sl)*4096)

#define OLOADB(buf) do { _Pragma("unroll") for (int nf = 0; nf < 2; ++nf) \
  _Pragma("unroll") for (int kk = 0; kk < 2; ++kk) \
    obreg[nf][kk] = *(const bf16x8*)(sB + (buf)*8192 + (wn*32 + nf*16 + fr)*64 + ((((kk<<2)|fq)^swz)<<3)); } while (0)
#define OLOADA_A(buf,q) do { _Pragma("unroll") for (int mm = 0; mm < 2; ++mm) \
  _Pragma("unroll") for (int kk = 0; kk < 2; ++kk) \
    oarA[mm][kk] = *(const bf16x8*)(sA + (buf)*8192 + (wm*64 + ((q)*2+mm)*16 + fr)*64 + ((((kk<<2)|fq)^swz)<<3)); } while (0)
#define OLOADA_B(buf,q) do { _Pragma("unroll") for (int mm = 0; mm < 2; ++mm) \
  _Pragma("unroll") for (int kk = 0; kk < 2; ++kk) \
    oarB[mm][kk] = *(const bf16x8*)(sA + (buf)*8192 + (wm*64 + ((q)*2+mm)*16 + fr)*64 + ((((kk<<2)|fq)^swz)<<3)); } while (0)
#define OMFMA8_A(q) do { _Pragma("unroll") for (int kk = 0; kk < 2; ++kk) \
  _Pragma("unroll") for (int mm = 0; mm < 2; ++mm) \
  _Pragma("unroll") for (int nf = 0; nf < 2; ++nf) \
    acc[(q)*2+mm][nf] = __builtin_amdgcn_mfma_f32_16x16x32_bf16(oarA[mm][kk], obreg[nf][kk], acc[(q)*2+mm][nf], 0, 0, 0); } while (0)
#define OMFMA8_B(q) do { _Pragma("unroll") for (int kk = 0; kk < 2; ++kk) \
  _Pragma("unroll") for (int mm = 0; mm < 2; ++mm) \
  _Pragma("unroll") for (int nf = 0; nf < 2; ++nf) \
    acc[(q)*2+mm][nf] = __builtin_amdgcn_mfma_f32_16x16x32_bf16(oarB[mm][kk], obreg[nf][kk], acc[(q)*2+mm][nf], 0, 0, 0); } while (0)

__global__ __launch_bounds__(512, 4) void out_gemm(
    const u16* __restrict__ ctx, const u16* __restrict__ wo,
    const float* __restrict__ bias, float* __restrict__ out)
{
  __shared__ alignas(1024) u16 sA[2 * 8192];
  __shared__ alignas(1024) u16 sB[2 * 8192];
  const int tid = threadIdx.x;
  const int lane = tid & 63, wid = tid >> 6;
  const int wm = wid >> 2, wn = wid & 3;
  const int fr = lane & 15, fq = lane >> 4;
  const int swz = fr & 7;
  const int m0 = blockIdx.x * 128, n0 = blockIdx.y * 128;

  const int r8 = tid >> 3, g8 = (tid & 7) ^ (r8 & 7);
  const u16* aSrcO = ctx + (size_t)(m0 + r8) * D_ + g8 * 8;
  const u16* bSrcO = wo  + (size_t)(n0 + r8) * D_ + g8 * 8;
  u16* aDstO = sA + wid * 512;
  u16* bDstO = sB + wid * 512;

  f32x4 acc[4][2];
  f32x4 z = {0.f, 0.f, 0.f, 0.f};
#pragma unroll
  for (int m = 0; m < 4; ++m)
#pragma unroll
    for (int n = 0; n < 2; ++n) acc[m][n] = z;

  bf16x8 obreg[2][2], oarA[2][2], oarB[2][2];

  OSTB(0,0,0); OSTB(1,0,0); OSTA(0,0,0); OSTA(1,0,0);
  OSTB(0,1,64); OSTB(1,1,64);
  asm volatile("s_waitcnt vmcnt(2)" ::: "memory");
  asm volatile("s_barrier" ::: "memory");

#pragma unroll 1
  for (int j = 0; j < 15; ++j) {
    const int kA1 = (2*j + 1) * 64;
    const int kB2 = (2*j + 2) * 64;
    const int kB3 = (2*j + 3) * 64;
    OLOADB(0); OLOADA_A(0,0); OLOADA_B(0,1); OSTA(0,1,kA1); OSTA(1,1,kA1);
      PH_MID(); OMFMA8_A(0); PH_END();
    OSTB(0,0,kB2); OSTB(1,0,kB2);
      PH_MID(); OMFMA8_B(1); PH_END_VM(2);
    OLOADB(1); OLOADA_A(1,0); OLOADA_B(1,1); OSTA(0,0,kB2); OSTA(1,0,kB2);
      PH_MID(); OMFMA8_A(0); PH_END();
    OSTB(0,1,kB3); OSTB(1,1,kB3);
      PH_MID(); OMFMA8_B(1); PH_END_VM(2);
  }
  {
    const int kA31 = 31 * 64;
    OLOADB(0); OLOADA_A(0,0); OLOADA_B(0,1); OSTA(0,1,kA31); OSTA(1,1,kA31);
      PH_MID(); OMFMA8_A(0); PH_END();
      PH_MID(); OMFMA8_B(1); PH_END_VM(0);
    OLOADB(1); OLOADA_A(1,0); OLOADA_B(1,1);
      PH_MID(); OMFMA8_A(0); PH_END();
      PH_MID(); OMFMA8_B(1); PH_END();
  }

#pragma unroll
  for (int mf = 0; mf < 4; ++mf)
#pragma unroll
    for (int nf = 0; nf < 2; ++nf) {
      int col = n0 + wn * 32 + nf * 16 + fr;
      float bv = bias[col];
#pragma unroll
      for (int r = 0; r < 4; ++r) {
        int row = m0 + wm * 64 + mf * 16 + fq * 4 + r;
        out[(size_t)row * D_ + col] = acc[mf][nf][r] + bv;
      }
    }
}

// ---------------- flash attention v4 + T5 setprio (round-14 proven state) ----------
#define STAGEKV(kvv, buf) do { _Pragma("unroll") \
  for (int i = 0; i < 4; ++i) { \
    int lk = i * 256 + tid; int rk = lk >> 4, sk = lk & 15; \
    gload_lds16(Kg + (size_t)((kvv) + rk) * HD_ + ((sk ^ (rk & 7)) << 3), \
                &Kl[buf][i * 2048 + wid * 512]); \
    int rv = lk >> 3, sv = lk & 7; \
    gload_lds16(Vg + (size_t)rv * S_ + (kvv) + ((sv ^ (rv & 7)) << 3), \
                &Vl[buf][i * 2048 + wid * 512]); \
  } } while (0)

__global__ __launch_bounds__(256, 2) void attn(
    const u16* __restrict__ qb, const u16* __restrict__ kb,
    const u16* __restrict__ vT, u16* __restrict__ ctx)
{
  __shared__ alignas(1024) u16 Kl[2][64 * 128];
  __shared__ alignas(1024) u16 Vl[2][128 * 64];
  __shared__ alignas(16) u16 Pl[4][32 * 64];

  const int tid = threadIdx.x, lane = tid & 63, wid = tid >> 6;
  const int fr = lane & 15, fq = lane >> 4;
  const int bh = blockIdx.y;
  const int q0 = blockIdx.x * 128 + wid * 32;
  f32x4 z = {0.f, 0.f, 0.f, 0.f};

  const u16* Kg = kb + (size_t)bh * S_ * HD_;
  const u16* Vg = vT + (size_t)bh * HD_ * S_;

  STAGEKV(0, 0);

  const u16* qbase = qb + ((size_t)bh * S_ + q0) * HD_;
  bf16x8 qa[2][4];
#pragma unroll
  for (int h = 0; h < 2; ++h)
#pragma unroll
    for (int kc = 0; kc < 4; ++kc)
      qa[h][kc] = *(const bf16x8*)(qbase + (size_t)(h * 16 + fr) * HD_ + kc * 32 + fq * 8);

  f32x4 accv[2][8];
#pragma unroll
  for (int h = 0; h < 2; ++h)
#pragma unroll
    for (int n = 0; n < 8; ++n) accv[h][n] = z;
  float m_run[2] = {-1e30f, -1e30f};
  float l_run[2] = {0.f, 0.f};

  __syncthreads();
  int cur = 0;

  for (int kv = 0; kv < S_; kv += 64) {
    if (kv + 64 < S_) STAGEKV(kv + 64, cur ^ 1);

    const u16* Kc = Kl[cur];
    const u16* Vc = Vl[cur];

    f32x4 sc[2][4];
    __builtin_amdgcn_s_setprio(1);
#pragma unroll
    for (int j = 0; j < 4; ++j) {
      f32x4 s0 = z, s1 = z;
#pragma unroll
      for (int kc = 0; kc < 4; ++kc) {
        int row = j * 16 + fr;
        bf16x8 kf = *(const bf16x8*)&Kc[row * 128 + ((kc * 32 + fq * 8) ^ ((row & 7) << 3))];
        s0 = __builtin_amdgcn_mfma_f32_16x16x32_bf16(kf, qa[0][kc], s0, 0, 0, 0);
        s1 = __builtin_amdgcn_mfma_f32_16x16x32_bf16(kf, qa[1][kc], s1, 0, 0, 0);
      }
      sc[0][j] = s0; sc[1][j] = s1;
    }
    __builtin_amdgcn_s_setprio(0);

    float pmax[2];
#pragma unroll
    for (int h = 0; h < 2; ++h) {
      float mx = sc[h][0][0];
#pragma unroll
      for (int j = 0; j < 4; ++j)
#pragma unroll
        for (int r = 0; r < 4; ++r) mx = fmaxf(mx, sc[h][j][r]);
      mx = fmaxf(mx, __shfl_xor(mx, 16));
      mx = fmaxf(mx, __shfl_xor(mx, 32));
      pmax[h] = mx;
    }

    int need = (pmax[0] > m_run[0] + 8.f) || (pmax[1] > m_run[1] + 8.f);
    if (__any(need)) {
#pragma unroll
      for (int h = 0; h < 2; ++h) {
        float mn = fmaxf(m_run[h], pmax[h]);
        float corr = __expf(m_run[h] - mn);
        m_run[h] = mn;
        l_run[h] *= corr;
#pragma unroll
        for (int r = 0; r < 4; ++r) {
          float rc = __shfl(corr, (lane & 48) | (fq * 4 + r));
#pragma unroll
          for (int n = 0; n < 8; ++n) accv[h][n][r] *= rc;
        }
      }
    }

    u16* Pw = Pl[wid];
#pragma unroll
    for (int h = 0; h < 2; ++h) {
      float ls = 0.f;
#pragma unroll
      for (int j = 0; j < 4; ++j) {
        union { u16 u[4]; ushort4 v; } pk;
#pragma unroll
        for (int r = 0; r < 4; ++r) {
          float p = __expf(sc[h][j][r] - m_run[h]);
          ls += p;
          pk.u[r] = f2bf(p);
        }
        int prow = h * 16 + fr;
        *(ushort4*)&Pw[prow * 64 + ((j * 16 + fq * 4) ^ ((fr & 7) << 3))] = pk.v;
      }
      ls += __shfl_xor(ls, 16);
      ls += __shfl_xor(ls, 32);
      l_run[h] += ls;
    }

    __builtin_amdgcn_s_setprio(1);
#pragma unroll
    for (int kc = 0; kc < 2; ++kc) {
      int pcol = (kc * 32 + fq * 8) ^ ((fr & 7) << 3);
      bf16x8 pa0 = *(const bf16x8*)&Pw[fr * 64 + pcol];
      bf16x8 pa1 = *(const bf16x8*)&Pw[(16 + fr) * 64 + pcol];
#pragma unroll
      for (int n = 0; n < 8; ++n) {
        int row = n * 16 + fr;
        bf16x8 vf = *(const bf16x8*)&Vc[row * 64 + ((kc * 32 + fq * 8) ^ ((row & 7) << 3))];
        accv[0][n] = __builtin_amdgcn_mfma_f32_16x16x32_bf16(pa0, vf, accv[0][n], 0, 0, 0);
        accv[1][n] = __builtin_amdgcn_mfma_f32_16x16x32_bf16(pa1, vf, accv[1][n], 0, 0, 0);
      }
    }
    __builtin_amdgcn_s_setprio(0);

    __syncthreads();
    cur ^= 1;
  }

  float inv[2][4];
#pragma unroll
  for (int h = 0; h < 2; ++h)
#pragma unroll
    for (int r = 0; r < 4; ++r) {
      float l = __shfl(l_run[h], (lane & 48) | (fq * 4 + r));
      inv[h][r] = 1.f / l;
    }
  u16* cb = ctx + (((size_t)(bh >> 4)) * S_ + q0) * D_ + (size_t)(bh & 15) * HD_;
#pragma unroll
  for (int h = 0; h < 2; ++h)
#pragma unroll
    for (int n = 0; n < 8; ++n)
#pragma unroll
      for (int r = 0; r < 4; ++r) {
        int q = h * 16 + fq * 4 + r;
        cb[(size_t)q * D_ + n * 16 + fr] = f2bf(accv[h][n][r] * inv[h][r]);
      }
}

// ---------------- launcher ----------------
extern "C" void kernel_launch(void* const* d_in, const int* in_sizes, int n_in,
                              void* d_out, int out_size, void* d_ws, size_t ws_size,
                              hipStream_t stream) {
  const float* hs   = (const float*)d_in[0];
  const float* wqkv = (const float*)d_in[1];
  const float* bqkv = (const float*)d_in[2];
  const float* wo   = (const float*)d_in[3];
  const float* bo   = (const float*)d_in[4];
  float* out = (float*)d_out;

  char* ws = (char*)d_ws;
  u16* hsb   = (u16*)(ws);                      // 16.0 MiB  (4096*2048)
  u16* wqkvb = (u16*)(ws + 16777216);           // 24.0 MiB  (6144*2048)
  u16* wob   = (u16*)(ws + 41943040);           //  8.0 MiB  (2048*2048)
  u16* qb    = (u16*)(ws + 50331648);           // 16.0 MiB  (B,H,S,HD) pre-scaled
  u16* kb    = (u16*)(ws + 67108864);           // 16.0 MiB
  u16* vT    = (u16*)(ws + 83886080);           // 16.0 MiB  (B,H,HD,S)
  u16* ctx   = (u16*)(ws + 100663296);          // 16.0 MiB  (B,S,D)

  cvt_all<<<2048, 256, 0, stream>>>(hs, wqkv, wo, hsb, wqkvb, wob);

  qkv_gemm<<<dim3(NTOK / 128, NQKV / 192), 512, 0, stream>>>(hsb, wqkvb, bqkv, qb, kb, vT);
  attn<<<dim3(S_ / 128, B_ * H_), 256, 0, stream>>>(qb, kb, vT, ctx);
  out_gemm<<<dim3(NTOK / 128, D_ / 128), 512, 0, stream>>>(ctx, wob, bo, out);
}

// Round 18
// 285.629 us; speedup vs baseline: 1.3953x; 1.3953x over previous
//
#include <hip/hip_runtime.h>
#include <cstdint>
#include <cstddef>

// Problem constants
#define B_ 2
#define S_ 2048
#define D_ 2048
#define H_ 16
#define HD_ 128
#define NTOK 4096       // B_*S_
#define NQKV 6144       // 3*D_

typedef unsigned short u16;
typedef __attribute__((ext_vector_type(8))) __bf16 bf16x8;
typedef __attribute__((ext_vector_type(4))) float f32x4;

// fp32 -> bf16 (RNE)
__device__ __forceinline__ u16 f2bf(float f) {
  uint32_t u = __builtin_bit_cast(uint32_t, f);
  u = (u + 0x7FFFu + ((u >> 16) & 1u)) >> 16;
  return (u16)u;
}

__device__ __forceinline__ void gload_lds16(const void* g, void* l) {
  __builtin_amdgcn_global_load_lds(
      (const __attribute__((address_space(1))) void*)g,
      (__attribute__((address_space(3))) void*)l, 16, 0, 0);
}

// ---------------- merged conversion kernel (3 tensors, one launch) ----------------
__global__ void cvt_all(const float* __restrict__ hs, const float* __restrict__ wqkv,
                        const float* __restrict__ wo,
                        u16* __restrict__ hsb, u16* __restrict__ wqkvb,
                        u16* __restrict__ wob) {
  const int n1 = (B_ * S_ * D_) / 8;
  const int n2 = n1 + (NQKV * D_) / 8;
  const int n3 = n2 + (D_ * D_) / 8;
  int idx = blockIdx.x * blockDim.x + threadIdx.x;
  int stride = gridDim.x * blockDim.x;
  for (int i = idx; i < n3; i += stride) {
    const float* src; u16* dst; int j;
    if (i < n1)      { src = hs;   dst = hsb;   j = i; }
    else if (i < n2) { src = wqkv; dst = wqkvb; j = i - n1; }
    else             { src = wo;   dst = wob;   j = i - n2; }
    const float4* s = (const float4*)(src + (size_t)j * 8);
    float4 a = s[0], b = s[1];
    union { u16 u[8]; uint4 v; } o;
    o.u[0] = f2bf(a.x); o.u[1] = f2bf(a.y); o.u[2] = f2bf(a.z); o.u[3] = f2bf(a.w);
    o.u[4] = f2bf(b.x); o.u[5] = f2bf(b.y); o.u[6] = f2bf(b.z); o.u[7] = f2bf(b.w);
    *(uint4*)(dst + (size_t)j * 8) = o.v;
  }
}

// ---------------- shared phase macros ----------------
#define PH_MID() do { asm volatile("s_barrier" ::: "memory"); \
  __builtin_amdgcn_s_setprio(1); } while (0)
#define PH_END() do { __builtin_amdgcn_s_setprio(0); \
  asm volatile("s_barrier" ::: "memory"); } while (0)
#define PH_END_VM(n) do { __builtin_amdgcn_s_setprio(0); \
  asm volatile("s_waitcnt vmcnt(" #n ")" ::: "memory"); \
  asm volatile("s_barrier" ::: "memory"); } while (0)

// ======== QKV GEMM: BM=128 x BN=192, BK=64, 80 KiB LDS, 2 blocks/CU (round-13) =====
// Proven 121us / 852 TF / MfmaUtil 38 / 0 conflicts. (Round-17 B-from-L2
// variant regressed to 239us — uncoalesced per-lane B loads; reverted.)

#define STA(sl,buf,ko) gload_lds16(aSrc + (size_t)(sl)*64*D_ + (ko), aDst + (buf)*8192  + (sl)*4096)
#define STB(sl,buf,ko) gload_lds16(bSrc + (size_t)(sl)*64*D_ + (ko), bDst + (buf)*12288 + (sl)*4096)

#define LOADB(buf) do { _Pragma("unroll") for (int nf = 0; nf < 3; ++nf) \
  _Pragma("unroll") for (int kk = 0; kk < 2; ++kk) \
    breg[nf][kk] = *(const bf16x8*)(sB + (buf)*12288 + (wn*48 + nf*16 + fr)*64 + ((((kk<<2)|fq)^swz)<<3)); } while (0)
#define LOADA_A(buf,q) do { _Pragma("unroll") for (int mm = 0; mm < 2; ++mm) \
  _Pragma("unroll") for (int kk = 0; kk < 2; ++kk) \
    arA[mm][kk] = *(const bf16x8*)(sA + (buf)*8192 + (wm*64 + ((q)*2+mm)*16 + fr)*64 + ((((kk<<2)|fq)^swz)<<3)); } while (0)
#define LOADA_B(buf,q) do { _Pragma("unroll") for (int mm = 0; mm < 2; ++mm) \
  _Pragma("unroll") for (int kk = 0; kk < 2; ++kk) \
    arB[mm][kk] = *(const bf16x8*)(sA + (buf)*8192 + (wm*64 + ((q)*2+mm)*16 + fr)*64 + ((((kk<<2)|fq)^swz)<<3)); } while (0)
#define MFMA12_A(q) do { _Pragma("unroll") for (int kk = 0; kk < 2; ++kk) \
  _Pragma("unroll") for (int mm = 0; mm < 2; ++mm) \
  _Pragma("unroll") for (int nf = 0; nf < 3; ++nf) \
    acc[(q)*2+mm][nf] = __builtin_amdgcn_mfma_f32_16x16x32_bf16(arA[mm][kk], breg[nf][kk], acc[(q)*2+mm][nf], 0, 0, 0); } while (0)
#define MFMA12_B(q) do { _Pragma("unroll") for (int kk = 0; kk < 2; ++kk) \
  _Pragma("unroll") for (int mm = 0; mm < 2; ++mm) \
  _Pragma("unroll") for (int nf = 0; nf < 3; ++nf) \
    acc[(q)*2+mm][nf] = __builtin_amdgcn_mfma_f32_16x16x32_bf16(arB[mm][kk], breg[nf][kk], acc[(q)*2+mm][nf], 0, 0, 0); } while (0)

__global__ __launch_bounds__(512, 4) void qkv_gemm(
    const u16* __restrict__ hsb, const u16* __restrict__ wb,
    const float* __restrict__ bias,
    u16* __restrict__ qb, u16* __restrict__ kb, u16* __restrict__ vT)
{
  __shared__ alignas(1024) u16 sA[2 * 8192];    // 32 KiB
  __shared__ alignas(1024) u16 sB[2 * 12288];   // 48 KiB  (total 80 -> 2 blocks/CU)
  const int tid = threadIdx.x;
  const int lane = tid & 63, wid = tid >> 6;
  const int wm = wid >> 2, wn = wid & 3;
  const int fr = lane & 15, fq = lane >> 4;
  const int swz = fr & 7;
  const int m0 = blockIdx.x * 128, n0 = blockIdx.y * 192;

  const int r8 = tid >> 3, g8 = (tid & 7) ^ (r8 & 7);
  const u16* aSrc = hsb + (size_t)(m0 + r8) * D_ + g8 * 8;
  const u16* bSrc = wb  + (size_t)(n0 + r8) * D_ + g8 * 8;
  u16* aDst = sA + wid * 512;
  u16* bDst = sB + wid * 512;

  f32x4 acc[4][3];
  f32x4 z = {0.f, 0.f, 0.f, 0.f};
#pragma unroll
  for (int m = 0; m < 4; ++m)
#pragma unroll
    for (int n = 0; n < 3; ++n) acc[m][n] = z;

  bf16x8 breg[3][2], arA[2][2], arB[2][2];

  STB(0,0,0); STB(1,0,0); STB(2,0,0); STA(0,0,0); STA(1,0,0);
  STB(0,1,64); STB(1,1,64); STB(2,1,64);
  asm volatile("s_waitcnt vmcnt(3)" ::: "memory");
  asm volatile("s_barrier" ::: "memory");

#pragma unroll 1
  for (int j = 0; j < 15; ++j) {
    const int kA1 = (2*j + 1) * 64;
    const int kB2 = (2*j + 2) * 64;
    const int kB3 = (2*j + 3) * 64;
    LOADB(0); LOADA_A(0,0); LOADA_B(0,1); STA(0,1,kA1); STA(1,1,kA1);
      PH_MID(); MFMA12_A(0); PH_END();
    STB(0,0,kB2); STB(1,0,kB2); STB(2,0,kB2);
      PH_MID(); MFMA12_B(1); PH_END_VM(3);
    LOADB(1); LOADA_A(1,0); LOADA_B(1,1); STA(0,0,kB2); STA(1,0,kB2);
      PH_MID(); MFMA12_A(0); PH_END();
    STB(0,1,kB3); STB(1,1,kB3); STB(2,1,kB3);
      PH_MID(); MFMA12_B(1); PH_END_VM(3);
  }
  {
    const int kA31 = 31 * 64;
    LOADB(0); LOADA_A(0,0); LOADA_B(0,1); STA(0,1,kA31); STA(1,1,kA31);
      PH_MID(); MFMA12_A(0); PH_END();
      PH_MID(); MFMA12_B(1); PH_END_VM(0);
    LOADB(1); LOADA_A(1,0); LOADA_B(1,1);
      PH_MID(); MFMA12_A(0); PH_END();
      PH_MID(); MFMA12_B(1); PH_END();
  }

  const float qscale = 0.08838834764831845f; // 1/sqrt(128)
#pragma unroll
  for (int mf = 0; mf < 4; ++mf)
#pragma unroll
    for (int nf = 0; nf < 3; ++nf) {
      int col = n0 + wn * 48 + nf * 16 + fr;
      float bv = bias[col];
      int t = col >> 11;
      int d2 = col & 2047;
      int h = d2 >> 7, hd = d2 & 127;
#pragma unroll
      for (int r = 0; r < 4; ++r) {
        int row = m0 + wm * 64 + mf * 16 + fq * 4 + r;
        int bb = row >> 11, s = row & 2047;
        int bh = bb * H_ + h;
        float val = acc[mf][nf][r] + bv;
        if (t == 0)      qb[((size_t)bh * S_ + s) * HD_ + hd] = f2bf(val * qscale);
        else if (t == 1) kb[((size_t)bh * S_ + s) * HD_ + hd] = f2bf(val);
        else             vT[((size_t)bh * HD_ + hd) * S_ + s] = f2bf(val);
      }
    }
}

// ======== OUT GEMM: BM=128 x BN=128, BK=64, 64 KiB, 2 blocks/CU (round-14) ========
#define OSTA(sl,buf,ko) gload_lds16(aSrcO + (size_t)(sl)*64*D_ + (ko), aDstO + (buf)*8192 + (sl)*4096)
#define OSTB(sl,buf,ko) gload_lds16(bSrcO + (size_t)(sl)*64*D_ + (ko), bDstO + (buf)*8192 + (sl)*4096)

#define OLOADB(buf) do { _Pragma("unroll") for (int nf = 0; nf < 2; ++nf) \
  _Pragma("unroll") for (int kk = 0; kk < 2; ++kk) \
    obreg[nf][kk] = *(const bf16x8*)(sB + (buf)*8192 + (wn*32 + nf*16 + fr)*64 + ((((kk<<2)|fq)^swz)<<3)); } while (0)
#define OLOADA_A(buf,q) do { _Pragma("unroll") for (int mm = 0; mm < 2; ++mm) \
  _Pragma("unroll") for (int kk = 0; kk < 2; ++kk) \
    oarA[mm][kk] = *(const bf16x8*)(sA + (buf)*8192 + (wm*64 + ((q)*2+mm)*16 + fr)*64 + ((((kk<<2)|fq)^swz)<<3)); } while (0)
#define OLOADA_B(buf,q) do { _Pragma("unroll") for (int mm = 0; mm < 2; ++mm) \
  _Pragma("unroll") for (int kk = 0; kk < 2; ++kk) \
    oarB[mm][kk] = *(const bf16x8*)(sA + (buf)*8192 + (wm*64 + ((q)*2+mm)*16 + fr)*64 + ((((kk<<2)|fq)^swz)<<3)); } while (0)
#define OMFMA8_A(q) do { _Pragma("unroll") for (int kk = 0; kk < 2; ++kk) \
  _Pragma("unroll") for (int mm = 0; mm < 2; ++mm) \
  _Pragma("unroll") for (int nf = 0; nf < 2; ++nf) \
    acc[(q)*2+mm][nf] = __builtin_amdgcn_mfma_f32_16x16x32_bf16(oarA[mm][kk], obreg[nf][kk], acc[(q)*2+mm][nf], 0, 0, 0); } while (0)
#define OMFMA8_B(q) do { _Pragma("unroll") for (int kk = 0; kk < 2; ++kk) \
  _Pragma("unroll") for (int mm = 0; mm < 2; ++mm) \
  _Pragma("unroll") for (int nf = 0; nf < 2; ++nf) \
    acc[(q)*2+mm][nf] = __builtin_amdgcn_mfma_f32_16x16x32_bf16(oarB[mm][kk], obreg[nf][kk], acc[(q)*2+mm][nf], 0, 0, 0); } while (0)

__global__ __launch_bounds__(512, 4) void out_gemm(
    const u16* __restrict__ ctx, const u16* __restrict__ wo,
    const float* __restrict__ bias, float* __restrict__ out)
{
  __shared__ alignas(1024) u16 sA[2 * 8192];
  __shared__ alignas(1024) u16 sB[2 * 8192];
  const int tid = threadIdx.x;
  const int lane = tid & 63, wid = tid >> 6;
  const int wm = wid >> 2, wn = wid & 3;
  const int fr = lane & 15, fq = lane >> 4;
  const int swz = fr & 7;
  const int m0 = blockIdx.x * 128, n0 = blockIdx.y * 128;

  const int r8 = tid >> 3, g8 = (tid & 7) ^ (r8 & 7);
  const u16* aSrcO = ctx + (size_t)(m0 + r8) * D_ + g8 * 8;
  const u16* bSrcO = wo  + (size_t)(n0 + r8) * D_ + g8 * 8;
  u16* aDstO = sA + wid * 512;
  u16* bDstO = sB + wid * 512;

  f32x4 acc[4][2];
  f32x4 z = {0.f, 0.f, 0.f, 0.f};
#pragma unroll
  for (int m = 0; m < 4; ++m)
#pragma unroll
    for (int n = 0; n < 2; ++n) acc[m][n] = z;

  bf16x8 obreg[2][2], oarA[2][2], oarB[2][2];

  OSTB(0,0,0); OSTB(1,0,0); OSTA(0,0,0); OSTA(1,0,0);
  OSTB(0,1,64); OSTB(1,1,64);
  asm volatile("s_waitcnt vmcnt(2)" ::: "memory");
  asm volatile("s_barrier" ::: "memory");

#pragma unroll 1
  for (int j = 0; j < 15; ++j) {
    const int kA1 = (2*j + 1) * 64;
    const int kB2 = (2*j + 2) * 64;
    const int kB3 = (2*j + 3) * 64;
    OLOADB(0); OLOADA_A(0,0); OLOADA_B(0,1); OSTA(0,1,kA1); OSTA(1,1,kA1);
      PH_MID(); OMFMA8_A(0); PH_END();
    OSTB(0,0,kB2); OSTB(1,0,kB2);
      PH_MID(); OMFMA8_B(1); PH_END_VM(2);
    OLOADB(1); OLOADA_A(1,0); OLOADA_B(1,1); OSTA(0,0,kB2); OSTA(1,0,kB2);
      PH_MID(); OMFMA8_A(0); PH_END();
    OSTB(0,1,kB3); OSTB(1,1,kB3);
      PH_MID(); OMFMA8_B(1); PH_END_VM(2);
  }
  {
    const int kA31 = 31 * 64;
    OLOADB(0); OLOADA_A(0,0); OLOADA_B(0,1); OSTA(0,1,kA31); OSTA(1,1,kA31);
      PH_MID(); OMFMA8_A(0); PH_END();
      PH_MID(); OMFMA8_B(1); PH_END_VM(0);
    OLOADB(1); OLOADA_A(1,0); OLOADA_B(1,1);
      PH_MID(); OMFMA8_A(0); PH_END();
      PH_MID(); OMFMA8_B(1); PH_END();
  }

#pragma unroll
  for (int mf = 0; mf < 4; ++mf)
#pragma unroll
    for (int nf = 0; nf < 2; ++nf) {
      int col = n0 + wn * 32 + nf * 16 + fr;
      float bv = bias[col];
#pragma unroll
      for (int r = 0; r < 4; ++r) {
        int row = m0 + wm * 64 + mf * 16 + fq * 4 + r;
        out[(size_t)row * D_ + col] = acc[mf][nf][r] + bv;
      }
    }
}

// ---------------- flash attention v4 + T5 setprio (round-14 proven state) ----------
#define STAGEKV(kvv, buf) do { _Pragma("unroll") \
  for (int i = 0; i < 4; ++i) { \
    int lk = i * 256 + tid; int rk = lk >> 4, sk = lk & 15; \
    gload_lds16(Kg + (size_t)((kvv) + rk) * HD_ + ((sk ^ (rk & 7)) << 3), \
                &Kl[buf][i * 2048 + wid * 512]); \
    int rv = lk >> 3, sv = lk & 7; \
    gload_lds16(Vg + (size_t)rv * S_ + (kvv) + ((sv ^ (rv & 7)) << 3), \
                &Vl[buf][i * 2048 + wid * 512]); \
  } } while (0)

__global__ __launch_bounds__(256, 2) void attn(
    const u16* __restrict__ qb, const u16* __restrict__ kb,
    const u16* __restrict__ vT, u16* __restrict__ ctx)
{
  __shared__ alignas(1024) u16 Kl[2][64 * 128];
  __shared__ alignas(1024) u16 Vl[2][128 * 64];
  __shared__ alignas(16) u16 Pl[4][32 * 64];

  const int tid = threadIdx.x, lane = tid & 63, wid = tid >> 6;
  const int fr = lane & 15, fq = lane >> 4;
  const int bh = blockIdx.y;
  const int q0 = blockIdx.x * 128 + wid * 32;
  f32x4 z = {0.f, 0.f, 0.f, 0.f};

  const u16* Kg = kb + (size_t)bh * S_ * HD_;
  const u16* Vg = vT + (size_t)bh * HD_ * S_;

  STAGEKV(0, 0);

  const u16* qbase = qb + ((size_t)bh * S_ + q0) * HD_;
  bf16x8 qa[2][4];
#pragma unroll
  for (int h = 0; h < 2; ++h)
#pragma unroll
    for (int kc = 0; kc < 4; ++kc)
      qa[h][kc] = *(const bf16x8*)(qbase + (size_t)(h * 16 + fr) * HD_ + kc * 32 + fq * 8);

  f32x4 accv[2][8];
#pragma unroll
  for (int h = 0; h < 2; ++h)
#pragma unroll
    for (int n = 0; n < 8; ++n) accv[h][n] = z;
  float m_run[2] = {-1e30f, -1e30f};
  float l_run[2] = {0.f, 0.f};

  __syncthreads();
  int cur = 0;

  for (int kv = 0; kv < S_; kv += 64) {
    if (kv + 64 < S_) STAGEKV(kv + 64, cur ^ 1);

    const u16* Kc = Kl[cur];
    const u16* Vc = Vl[cur];

    f32x4 sc[2][4];
    __builtin_amdgcn_s_setprio(1);
#pragma unroll
    for (int j = 0; j < 4; ++j) {
      f32x4 s0 = z, s1 = z;
#pragma unroll
      for (int kc = 0; kc < 4; ++kc) {
        int row = j * 16 + fr;
        bf16x8 kf = *(const bf16x8*)&Kc[row * 128 + ((kc * 32 + fq * 8) ^ ((row & 7) << 3))];
        s0 = __builtin_amdgcn_mfma_f32_16x16x32_bf16(kf, qa[0][kc], s0, 0, 0, 0);
        s1 = __builtin_amdgcn_mfma_f32_16x16x32_bf16(kf, qa[1][kc], s1, 0, 0, 0);
      }
      sc[0][j] = s0; sc[1][j] = s1;
    }
    __builtin_amdgcn_s_setprio(0);

    float pmax[2];
#pragma unroll
    for (int h = 0; h < 2; ++h) {
      float mx = sc[h][0][0];
#pragma unroll
      for (int j = 0; j < 4; ++j)
#pragma unroll
        for (int r = 0; r < 4; ++r) mx = fmaxf(mx, sc[h][j][r]);
      mx = fmaxf(mx, __shfl_xor(mx, 16));
      mx = fmaxf(mx, __shfl_xor(mx, 32));
      pmax[h] = mx;
    }

    int need = (pmax[0] > m_run[0] + 8.f) || (pmax[1] > m_run[1] + 8.f);
    if (__any(need)) {
#pragma unroll
      for (int h = 0; h < 2; ++h) {
        float mn = fmaxf(m_run[h], pmax[h]);
        float corr = __expf(m_run[h] - mn);
        m_run[h] = mn;
        l_run[h] *= corr;
#pragma unroll
        for (int r = 0; r < 4; ++r) {
          float rc = __shfl(corr, (lane & 48) | (fq * 4 + r));
#pragma unroll
          for (int n = 0; n < 8; ++n) accv[h][n][r] *= rc;
        }
      }
    }

    u16* Pw = Pl[wid];
#pragma unroll
    for (int h = 0; h < 2; ++h) {
      float ls = 0.f;
#pragma unroll
      for (int j = 0; j < 4; ++j) {
        union { u16 u[4]; ushort4 v; } pk;
#pragma unroll
        for (int r = 0; r < 4; ++r) {
          float p = __expf(sc[h][j][r] - m_run[h]);
          ls += p;
          pk.u[r] = f2bf(p);
        }
        int prow = h * 16 + fr;
        *(ushort4*)&Pw[prow * 64 + ((j * 16 + fq * 4) ^ ((fr & 7) << 3))] = pk.v;
      }
      ls += __shfl_xor(ls, 16);
      ls += __shfl_xor(ls, 32);
      l_run[h] += ls;
    }

    __builtin_amdgcn_s_setprio(1);
#pragma unroll
    for (int kc = 0; kc < 2; ++kc) {
      int pcol = (kc * 32 + fq * 8) ^ ((fr & 7) << 3);
      bf16x8 pa0 = *(const bf16x8*)&Pw[fr * 64 + pcol];
      bf16x8 pa1 = *(const bf16x8*)&Pw[(16 + fr) * 64 + pcol];
#pragma unroll
      for (int n = 0; n < 8; ++n) {
        int row = n * 16 + fr;
        bf16x8 vf = *(const bf16x8*)&Vc[row * 64 + ((kc * 32 + fq * 8) ^ ((row & 7) << 3))];
        accv[0][n] = __builtin_amdgcn_mfma_f32_16x16x32_bf16(pa0, vf, accv[0][n], 0, 0, 0);
        accv[1][n] = __builtin_amdgcn_mfma_f32_16x16x32_bf16(pa1, vf, accv[1][n], 0, 0, 0);
      }
    }
    __builtin_amdgcn_s_setprio(0);

    __syncthreads();
    cur ^= 1;
  }

  float inv[2][4];
#pragma unroll
  for (int h = 0; h < 2; ++h)
#pragma unroll
    for (int r = 0; r < 4; ++r) {
      float l = __shfl(l_run[h], (lane & 48) | (fq * 4 + r));
      inv[h][r] = 1.f / l;
    }
  u16* cb = ctx + (((size_t)(bh >> 4)) * S_ + q0) * D_ + (size_t)(bh & 15) * HD_;
#pragma unroll
  for (int h = 0; h < 2; ++h)
#pragma unroll
    for (int n = 0; n < 8; ++n)
#pragma unroll
      for (int r = 0; r < 4; ++r) {
        int q = h * 16 + fq * 4 + r;
        cb[(size_t)q * D_ + n * 16 + fr] = f2bf(accv[h][n][r] * inv[h][r]);
      }
}

// ---------------- launcher ----------------
extern "C" void kernel_launch(void* const* d_in, const int* in_sizes, int n_in,
                              void* d_out, int out_size, void* d_ws, size_t ws_size,
                              hipStream_t stream) {
  const float* hs   = (const float*)d_in[0];
  const float* wqkv = (const float*)d_in[1];
  const float* bqkv = (const float*)d_in[2];
  const float* wo   = (const float*)d_in[3];
  const float* bo   = (const float*)d_in[4];
  float* out = (float*)d_out;

  char* ws = (char*)d_ws;
  u16* hsb   = (u16*)(ws);                      // 16.0 MiB  (4096*2048)
  u16* wqkvb = (u16*)(ws + 16777216);           // 24.0 MiB  (6144*2048)
  u16* wob   = (u16*)(ws + 41943040);           //  8.0 MiB  (2048*2048)
  u16* qb    = (u16*)(ws + 50331648);           // 16.0 MiB  (B,H,S,HD) pre-scaled
  u16* kb    = (u16*)(ws + 67108864);           // 16.0 MiB
  u16* vT    = (u16*)(ws + 83886080);           // 16.0 MiB  (B,H,HD,S)
  u16* ctx   = (u16*)(ws + 100663296);          // 16.0 MiB  (B,S,D)

  cvt_all<<<2048, 256, 0, stream>>>(hs, wqkv, wo, hsb, wqkvb, wob);

  qkv_gemm<<<dim3(NTOK / 128, NQKV / 192), 512, 0, stream>>>(hsb, wqkvb, bqkv, qb, kb, vT);
  attn<<<dim3(S_ / 128, B_ * H_), 256, 0, stream>>>(qb, kb, vT, ctx);
  out_gemm<<<dim3(NTOK / 128, D_ / 128), 512, 0, stream>>>(ctx, wob, bo, out);
}